// Round 2
// baseline (207.978 us; speedup 1.0000x reference)
//
#include <hip/hip_runtime.h>
#include <stdint.h>

#define RX 128
#define NBU 32      // BS*UE

typedef __attribute__((ext_vector_type(8))) short short8;   // 8 bf16 (4 VGPRs)
typedef __attribute__((ext_vector_type(4))) float f32x4;

// ws layout (floats):
//   R1 @ 0        [4096*64]   dot(x_row, W1[:,  0: 64])
//   R2 @ 262144   [4096*64]   dot(x_row, W1[:, 64:128])
//   R3 @ 524288   [4096*64]   dot(x_row, W1[:,128:192])
//   r4 @ 786432   [32*64]     dot(m_bu,  W1[:,192:256])
//   r5b@ 788480   [32*64]     dot(m_bu,  W1[:,256:320]) + b1
#define WS_R1 0
#define WS_R2 262144
#define WS_R3 524288
#define WS_R4 786432
#define WS_R5 788480

// hardware RNE f32x2 -> packed bf16x2
__device__ __forceinline__ uint32_t cvtpk(float a, float b) {
    uint32_t r;
    asm("v_cvt_pk_bf16_f32 %0, %1, %2" : "=v"(r) : "v"(a), "v"(b));
    return r;
}

union S8U4 { short8 s8; uint32_t u[4]; };

__device__ __forceinline__ short8 pack8(const float* __restrict__ y) {
    S8U4 t;
    t.u[0] = cvtpk(y[0], y[1]);
    t.u[1] = cvtpk(y[2], y[3]);
    t.u[2] = cvtpk(y[4], y[5]);
    t.u[3] = cvtpk(y[6], y[7]);
    return t.s8;
}

// load 16 floats (two 8-float halves at d0 and d1) into o[0..15]
__device__ __forceinline__ void ld16f(const float* __restrict__ p, int d0, int d1,
                                      float* __restrict__ o) {
    *(float4*)(o + 0)  = *(const float4*)(p + d0);
    *(float4*)(o + 4)  = *(const float4*)(p + d0 + 4);
    *(float4*)(o + 8)  = *(const float4*)(p + d1);
    *(float4*)(o + 12) = *(const float4*)(p + d1 + 4);
}

// ---------------- kernel 1: precompute R1,R2,R3 (blocks 0..511) and r4,r5b (512..543)
// (unchanged — ~4 µs, not the bottleneck)
__global__ __launch_bounds__(192) void k_pre(const float* __restrict__ x,
                                             const float* __restrict__ W1,
                                             const float* __restrict__ b1,
                                             float* __restrict__ ws) {
    __shared__ float s[8256];
    const int t = threadIdx.x;
    const int blk = blockIdx.x;

    if (blk < 512) {
        const int r0 = blk * 8;                       // 8 rows of Xall per block
        if (t < 128)
            ((float4*)s)[t] = ((const float4*)(x + r0 * 64))[t];
        __syncthreads();
        const int arr = t >> 6;                       // 0->R1, 1->R2, 2->R3
        const int dp  = t & 63;
        const float* wrow = W1 + dp * 320 + arr * 64; // W1[dp][arr*64 + f]
        float4 w[16];
#pragma unroll
        for (int fc = 0; fc < 16; ++fc) w[fc] = ((const float4*)wrow)[fc];
        float* dst = ws + (arr == 0 ? WS_R1 : arr == 1 ? WS_R2 : WS_R3);
#pragma unroll
        for (int r = 0; r < 8; ++r) {
            float acc = 0.f;
#pragma unroll
            for (int fc = 0; fc < 16; ++fc) {
                float4 xv = ((const float4*)(s + r * 64))[fc];
                acc = fmaf(xv.x, w[fc].x, acc);
                acc = fmaf(xv.y, w[fc].y, acc);
                acc = fmaf(xv.z, w[fc].z, acc);
                acc = fmaf(xv.w, w[fc].w, acc);
            }
            dst[(r0 + r) * 64 + dp] = acc;
        }
    } else {
        const int bu = blk - 512;
        const float* xb = x + bu * RX * 64;
        for (int idx = t; idx < 2048; idx += 192)
            ((float4*)s)[idx] = ((const float4*)xb)[idx];
        __syncthreads();
        if (t < 64) {                                  // column means
            float a0 = 0, a1 = 0, a2 = 0, a3 = 0;
            for (int r = 0; r < 128; r += 4) {
                a0 += s[(r + 0) * 64 + t];
                a1 += s[(r + 1) * 64 + t];
                a2 += s[(r + 2) * 64 + t];
                a3 += s[(r + 3) * 64 + t];
            }
            s[8192 + t] = (a0 + a1 + a2 + a3) * (1.0f / 128.0f);
        }
        __syncthreads();
        if (t < 128) {
            const int dp = t & 63, which = t >> 6;     // 0->r4, 1->r5b
            const float* wrow = W1 + dp * 320 + 192 + which * 64;
            float acc = which ? b1[dp] : 0.f;
#pragma unroll
            for (int fc = 0; fc < 16; ++fc) {
                float4 mv = ((const float4*)(s + 8192))[fc];
                float4 wv = ((const float4*)wrow)[fc];
                acc = fmaf(mv.x, wv.x, acc);
                acc = fmaf(mv.y, wv.y, acc);
                acc = fmaf(mv.z, wv.z, acc);
                acc = fmaf(mv.w, wv.w, acc);
            }
            (ws + (which ? WS_R5 : WS_R4))[bu * 64 + dp] = acc;
        }
    }
}

// ---------------- kernel 2: one block per (bu, 4-row group)
// vs round-1:
//  * R3 fragments live in REGISTERS (ip-invariant; 32 floats/lane) — sR3 LDS tile,
//    staging loop, and the only __syncthreads are gone.
//  * Epilogue: wave's 16x64 f32 tile round-trips a wave-private XOR-swizzled LDS
//    region, then 4x 1KB-contiguous nontemporal dwordx4 stores (was 16 scattered
//    64B segments per instr; nt keeps 128 MiB of streaming writes out of L2).
__global__ __launch_bounds__(256, 3) void k_main(const float* __restrict__ ws,
                                                 const float* __restrict__ ln_g,
                                                 const float* __restrict__ ln_b,
                                                 const float* __restrict__ bias,
                                                 const float* __restrict__ W2,
                                                 const float* __restrict__ b2,
                                                 float* __restrict__ out) {
    const float* R1  = ws + WS_R1;
    const float* R2  = ws + WS_R2;
    const float* R3  = ws + WS_R3;
    const float* r4  = ws + WS_R4;
    const float* r5b = ws + WS_R5;

    __shared__ float sEpi[8192];     // 4 waves × 2 ping-pong regions × 1024 floats = 32 KB

    const int t    = threadIdx.x;
    const int lane = t & 63;
    const int wid  = t >> 6;        // wave id 0..3
    const int q    = lane >> 4;     // quad 0..3
    const int ml   = lane & 15;
    const int bu   = blockIdx.x >> 5;
    const int i0   = (blockIdx.x & 31) * 4;

    const int d0 = q * 8;           // k-tile 0 d-range [d0, d0+8)
    const int d1 = 32 + q * 8;      // k-tile 1 d-range [d1, d1+8)

    // ---- R3 fragments in registers (ip-invariant): tiles jt = wid and wid+4,
    //      row jt*16+ml, this lane's d-slice. Exactly what the old sR3 reads gave.
    float r3f[2][16];
#pragma unroll
    for (int tt = 0; tt < 2; ++tt) {
        const int jt = wid + tt * 4;
        const float* rp = R3 + (size_t)bu * 8192 + (jt * 16 + ml) * 64;
        ld16f(rp, d0, d1, r3f[tt]);
    }

    // ---- per-lane constants over this lane's d-set
    float gv[16], bbv[16];
    ld16f(ln_g, d0, d1, gv);
    ld16f(ln_b, d0, d1, bbv);

    // W2 fragments (A-operand): frag[m=ml][k=q*8+jj] = W2[ot*16+ml][kt*32+q*8+jj]
    short8 bf[4][2];
#pragma unroll
    for (int ot = 0; ot < 4; ++ot) {
#pragma unroll
        for (int kt = 0; kt < 2; ++kt) {
            const float* wp = W2 + (ot * 16 + ml) * 64 + kt * 32 + q * 8;
            float4 w0 = *(const float4*)wp;
            float4 w1 = *(const float4*)(wp + 4);
            S8U4 v;
            v.u[0] = cvtpk(w0.x, w0.y);
            v.u[1] = cvtpk(w0.z, w0.w);
            v.u[2] = cvtpk(w1.x, w1.y);
            v.u[3] = cvtpk(w1.z, w1.w);
            bf[ot][kt] = v.s8;
        }
    }
    // C-init: D^T row m = q*4+reg -> b2[ot*16 + q*4 + reg]
    f32x4 b2q[4];
#pragma unroll
    for (int ot = 0; ot < 4; ++ot)
        b2q[ot] = *(const f32x4*)(b2 + ot * 16 + q * 4);

#pragma unroll
    for (int ip = 0; ip < 4; ++ip) {
        const int i   = i0 + ip;
        const int row = bu * 128 + i;
        const int it  = i >> 4, im = i & 15;

        float basev[16], tv[16];
        ld16f(R2 + (size_t)row * 64, d0, d1, basev);
        ld16f(r5b + bu * 64, d0, d1, tv);
#pragma unroll
        for (int s = 0; s < 16; ++s) basev[s] += tv[s];

#pragma unroll
        for (int p = 0; p < 2; ++p) {
            const int jt = p * 4 + wid;      // j-tile handled by this wave this pass

            float h[16];
#pragma unroll
            for (int s = 0; s < 16; ++s) h[s] = r3f[p][s] + basev[s];

            const bool diag = (jt == it) && (ml == im);   // j == i
            if (diag) {
                float da[16], db[16];
                ld16f(R1 + (size_t)row * 64, d0, d1, da);
                ld16f(r4 + bu * 64, d0, d1, db);
#pragma unroll
                for (int s = 0; s < 16; ++s) h[s] += da[s] + db[s];
            }

            // LayerNorm over d=64: 16 in-lane + lanes {ml, ml+16, ml+32, ml+48}
            float sum = 0.f, ss = 0.f;
#pragma unroll
            for (int s = 0; s < 16; ++s) { sum += h[s]; ss = fmaf(h[s], h[s], ss); }
            sum += __shfl_xor(sum, 16); sum += __shfl_xor(sum, 32);
            ss  += __shfl_xor(ss, 16);  ss  += __shfl_xor(ss, 32);
            const float mu  = sum * 0.015625f;
            const float var = ss * 0.015625f - mu * mu;
            const float inv = rsqrtf(var + 1e-5f);
            const float nmi = -mu * inv;

#pragma unroll
            for (int s = 0; s < 16; ++s) {
                float v = fmaf(fmaf(h[s], inv, nmi), gv[s], bbv[s]);
                h[s] = fmaxf(v, 0.f);
            }
            if (diag) {
                float bi[16];
                ld16f(bias, d0, d1, bi);
#pragma unroll
                for (int s = 0; s < 16; ++s) h[s] += bi[s];
            }

            // pack y fragments (B-operand: B[k=q*8+jj][n=ml] = y[j][d])
            const short8 a0 = pack8(h);
            const short8 a1 = pack8(h + 8);

            // MFMA + LDS-transpose epilogue.
            // D^T: lane(q,ml) reg r = out[j=jt*16+ml][o=ot*16+q*4+r].
            // Write swizzled (conflict-free), read back lane-linear, nt-store 1KB/instr.
            float* ep = sEpi + wid * 2048 + (((ip << 1) + p) & 1) * 1024;
#pragma unroll
            for (int ot = 0; ot < 4; ++ot) {
                f32x4 acc = b2q[ot];
                acc = __builtin_amdgcn_mfma_f32_16x16x32_bf16(bf[ot][0], a0, acc, 0, 0, 0);
                acc = __builtin_amdgcn_mfma_f32_16x16x32_bf16(bf[ot][1], a1, acc, 0, 0, 0);
                const int off = (ot * 16 + q * 4) ^ ((ml & 7) << 3);
                *(f32x4*)(ep + ml * 64 + off) = acc;
            }
            float* gb = out + (size_t)row * 8192 + jt * 1024;
#pragma unroll
            for (int c = 0; c < 4; ++c) {
                const int F  = c * 256 + lane * 4;     // linear float idx in 16x64 tile
                const int jl = F >> 6;
                const int o  = F & 63;
                f32x4 v = *(const f32x4*)(ep + jl * 64 + (o ^ ((jl & 7) << 3)));
                __builtin_nontemporal_store(v, (f32x4*)(gb + F));
            }
        }
    }
}

extern "C" void kernel_launch(void* const* d_in, const int* in_sizes, int n_in,
                              void* d_out, int out_size, void* d_ws, size_t ws_size,
                              hipStream_t stream) {
    const float* x    = (const float*)d_in[0];
    const float* W1   = (const float*)d_in[1];
    const float* b1   = (const float*)d_in[2];
    const float* ln_g = (const float*)d_in[3];
    const float* ln_b = (const float*)d_in[4];
    const float* bias = (const float*)d_in[5];
    const float* W2   = (const float*)d_in[6];
    const float* b2   = (const float*)d_in[7];
    float* ws  = (float*)d_ws;
    float* out = (float*)d_out;

    hipLaunchKernelGGL(k_pre, dim3(544), dim3(192), 0, stream, x, W1, b1, ws);
    hipLaunchKernelGGL(k_main, dim3(1024), dim3(256), 0, stream,
                       ws, ln_g, ln_b, bias, W2, b2, out);
}

// Round 3
// 172.100 us; speedup vs baseline: 1.2085x; 1.2085x over previous
//
#include <hip/hip_runtime.h>
#include <stdint.h>

#define RX 128
#define NBU 32      // BS*UE

typedef __attribute__((ext_vector_type(8))) short short8;   // 8 bf16 (4 VGPRs)
typedef __attribute__((ext_vector_type(4))) float f32x4;

// ws layout (floats):
//   R1 @ 0        [4096*64]   dot(x_row, W1[:,  0: 64])
//   R2 @ 262144   [4096*64]   dot(x_row, W1[:, 64:128])
//   R3 @ 524288   [4096*64]   dot(x_row, W1[:,128:192])
//   r4 @ 786432   [32*64]     dot(m_bu,  W1[:,192:256])
//   r5b@ 788480   [32*64]     dot(m_bu,  W1[:,256:320]) + b1
#define WS_R1 0
#define WS_R2 262144
#define WS_R3 524288
#define WS_R4 786432
#define WS_R5 788480

#define LDP 68      // padded row stride (floats) for the LDS R3 tile

// hardware RNE f32x2 -> packed bf16x2
__device__ __forceinline__ uint32_t cvtpk(float a, float b) {
    uint32_t r;
    asm("v_cvt_pk_bf16_f32 %0, %1, %2" : "=v"(r) : "v"(a), "v"(b));
    return r;
}

union S8U4 { short8 s8; uint32_t u[4]; };

__device__ __forceinline__ short8 pack8(const float* __restrict__ y) {
    S8U4 t;
    t.u[0] = cvtpk(y[0], y[1]);
    t.u[1] = cvtpk(y[2], y[3]);
    t.u[2] = cvtpk(y[4], y[5]);
    t.u[3] = cvtpk(y[6], y[7]);
    return t.s8;
}

// load 16 floats (two 8-float halves at d0 and d1) into o[0..15]
__device__ __forceinline__ void ld16f(const float* __restrict__ p, int d0, int d1,
                                      float* __restrict__ o) {
    *(float4*)(o + 0)  = *(const float4*)(p + d0);
    *(float4*)(o + 4)  = *(const float4*)(p + d0 + 4);
    *(float4*)(o + 8)  = *(const float4*)(p + d1);
    *(float4*)(o + 12) = *(const float4*)(p + d1 + 4);
}

// ---------------- kernel 1: precompute R1,R2,R3 (blocks 0..511) and r4,r5b (512..543)
// (unchanged — not the bottleneck)
__global__ __launch_bounds__(192) void k_pre(const float* __restrict__ x,
                                             const float* __restrict__ W1,
                                             const float* __restrict__ b1,
                                             float* __restrict__ ws) {
    __shared__ float s[8256];
    const int t = threadIdx.x;
    const int blk = blockIdx.x;

    if (blk < 512) {
        const int r0 = blk * 8;                       // 8 rows of Xall per block
        if (t < 128)
            ((float4*)s)[t] = ((const float4*)(x + r0 * 64))[t];
        __syncthreads();
        const int arr = t >> 6;                       // 0->R1, 1->R2, 2->R3
        const int dp  = t & 63;
        const float* wrow = W1 + dp * 320 + arr * 64; // W1[dp][arr*64 + f]
        float4 w[16];
#pragma unroll
        for (int fc = 0; fc < 16; ++fc) w[fc] = ((const float4*)wrow)[fc];
        float* dst = ws + (arr == 0 ? WS_R1 : arr == 1 ? WS_R2 : WS_R3);
#pragma unroll
        for (int r = 0; r < 8; ++r) {
            float acc = 0.f;
#pragma unroll
            for (int fc = 0; fc < 16; ++fc) {
                float4 xv = ((const float4*)(s + r * 64))[fc];
                acc = fmaf(xv.x, w[fc].x, acc);
                acc = fmaf(xv.y, w[fc].y, acc);
                acc = fmaf(xv.z, w[fc].z, acc);
                acc = fmaf(xv.w, w[fc].w, acc);
            }
            dst[(r0 + r) * 64 + dp] = acc;
        }
    } else {
        const int bu = blk - 512;
        const float* xb = x + bu * RX * 64;
        for (int idx = t; idx < 2048; idx += 192)
            ((float4*)s)[idx] = ((const float4*)xb)[idx];
        __syncthreads();
        if (t < 64) {                                  // column means
            float a0 = 0, a1 = 0, a2 = 0, a3 = 0;
            for (int r = 0; r < 128; r += 4) {
                a0 += s[(r + 0) * 64 + t];
                a1 += s[(r + 1) * 64 + t];
                a2 += s[(r + 2) * 64 + t];
                a3 += s[(r + 3) * 64 + t];
            }
            s[8192 + t] = (a0 + a1 + a2 + a3) * (1.0f / 128.0f);
        }
        __syncthreads();
        if (t < 128) {
            const int dp = t & 63, which = t >> 6;     // 0->r4, 1->r5b
            const float* wrow = W1 + dp * 320 + 192 + which * 64;
            float acc = which ? b1[dp] : 0.f;
#pragma unroll
            for (int fc = 0; fc < 16; ++fc) {
                float4 mv = ((const float4*)(s + 8192))[fc];
                float4 wv = ((const float4*)wrow)[fc];
                acc = fmaf(mv.x, wv.x, acc);
                acc = fmaf(mv.y, wv.y, acc);
                acc = fmaf(mv.z, wv.z, acc);
                acc = fmaf(mv.w, wv.w, acc);
            }
            (ws + (which ? WS_R5 : WS_R4))[bu * 64 + dp] = acc;
        }
    }
}

// ---------------- kernel 2: one block per (bu, 4-row group)
// = round-1 structure (sR3 staged in LDS, no nt, no extra persistent VGPRs), plus:
//  * LDS-transpose epilogue with NORMAL stores: wave's 16x64 f32 D^T tile goes
//    through a wave-private 4KB swizzled LDS region, emitted as 4x 1KB-contiguous
//    dwordx4 stores -> guaranteed full 128B-line coverage per instruction (no
//    partial-line write-allocate fetches). Cached path (L2 combines + absorbs).
//  * bijective XCD swizzle: all 32 blocks of a bu land on one XCD -> R2/R3 L2-hot.
__global__ __launch_bounds__(256, 3) void k_main(const float* __restrict__ ws,
                                                 const float* __restrict__ ln_g,
                                                 const float* __restrict__ ln_b,
                                                 const float* __restrict__ bias,
                                                 const float* __restrict__ W2,
                                                 const float* __restrict__ b2,
                                                 float* __restrict__ out) {
    const float* R1  = ws + WS_R1;
    const float* R2  = ws + WS_R2;
    const float* R3  = ws + WS_R3;
    const float* r4  = ws + WS_R4;
    const float* r5b = ws + WS_R5;

    __shared__ float sR3[128 * LDP];   // 34816 B
    __shared__ float sEpi[4096];       // 4 waves x 1024 floats = 16 KB (total 51200 B -> 3 blk/CU)

    const int t    = threadIdx.x;
    const int lane = t & 63;
    const int wid  = t >> 6;        // wave id 0..3
    const int q    = lane >> 4;     // quad 0..3
    const int ml   = lane & 15;

    // XCD swizzle: blk = 8a+r -> r*128+a. Consecutive blockIdx round-robin XCDs,
    // so all 32 blocks of one bu get the same r (= same XCD). Bijective on [0,1024).
    const int nb  = (blockIdx.x & 7) * 128 + (blockIdx.x >> 3);
    const int bu  = nb >> 5;
    const int i0  = (nb & 31) * 4;

    const int d0 = q * 8;           // k-tile 0 d-range [d0, d0+8)
    const int d1 = 32 + q * 8;      // k-tile 1 d-range [d1, d1+8)

    // ---- stage R3[bu] (128x64) into LDS, coalesced, padded rows
    {
        const float* r3g = R3 + (size_t)bu * 8192;
#pragma unroll
        for (int c = 0; c < 8; ++c) {
            const int g = c * 256 + t;            // float4 index 0..2047
            const int r = g >> 4, col = (g & 15) << 2;
            *(float4*)&sR3[r * LDP + col] = ((const float4*)r3g)[g];
        }
    }

    // ---- per-lane constants over this lane's d-set
    float gv[16], bbv[16];
    ld16f(ln_g, d0, d1, gv);
    ld16f(ln_b, d0, d1, bbv);

    // W2 fragments (A-operand): frag[m=ml][k=q*8+jj] = W2[ot*16+ml][kt*32+q*8+jj]
    short8 bf[4][2];
#pragma unroll
    for (int ot = 0; ot < 4; ++ot) {
#pragma unroll
        for (int kt = 0; kt < 2; ++kt) {
            const float* wp = W2 + (ot * 16 + ml) * 64 + kt * 32 + q * 8;
            float4 w0 = *(const float4*)wp;
            float4 w1 = *(const float4*)(wp + 4);
            S8U4 v;
            v.u[0] = cvtpk(w0.x, w0.y);
            v.u[1] = cvtpk(w0.z, w0.w);
            v.u[2] = cvtpk(w1.x, w1.y);
            v.u[3] = cvtpk(w1.z, w1.w);
            bf[ot][kt] = v.s8;
        }
    }
    // C-init: D^T row m = q*4+reg -> b2[ot*16 + q*4 + reg]
    f32x4 b2q[4];
#pragma unroll
    for (int ot = 0; ot < 4; ++ot)
        b2q[ot] = *(const f32x4*)(b2 + ot * 16 + q * 4);

    __syncthreads();

    float* ep = sEpi + wid * 1024;   // wave-private epilogue region (same-wave DS ordering)

#pragma unroll
    for (int ip = 0; ip < 4; ++ip) {
        const int i   = i0 + ip;
        const int row = bu * 128 + i;
        const int it  = i >> 4, im = i & 15;

        float basev[16], tv[16];
        ld16f(R2 + (size_t)row * 64, d0, d1, basev);
        ld16f(r5b + bu * 64, d0, d1, tv);
#pragma unroll
        for (int s = 0; s < 16; ++s) basev[s] += tv[s];

#pragma unroll
        for (int p = 0; p < 2; ++p) {
            const int jt = p * 4 + wid;      // j-tile handled by this wave this pass
            const int j  = jt * 16 + ml;     // this lane's j (column) index

            float h[16];
            {
                const float* sp = sR3 + j * LDP;
                *(float4*)(h + 0)  = *(const float4*)(sp + d0);
                *(float4*)(h + 4)  = *(const float4*)(sp + d0 + 4);
                *(float4*)(h + 8)  = *(const float4*)(sp + d1);
                *(float4*)(h + 12) = *(const float4*)(sp + d1 + 4);
            }
#pragma unroll
            for (int s = 0; s < 16; ++s) h[s] += basev[s];

            const bool diag = (jt == it) && (ml == im);   // j == i
            if (diag) {
                float da[16], db[16];
                ld16f(R1 + (size_t)row * 64, d0, d1, da);
                ld16f(r4 + bu * 64, d0, d1, db);
#pragma unroll
                for (int s = 0; s < 16; ++s) h[s] += da[s] + db[s];
            }

            // LayerNorm over d=64: 16 in-lane + lanes {ml, ml+16, ml+32, ml+48}
            float sum = 0.f, ss = 0.f;
#pragma unroll
            for (int s = 0; s < 16; ++s) { sum += h[s]; ss = fmaf(h[s], h[s], ss); }
            sum += __shfl_xor(sum, 16); sum += __shfl_xor(sum, 32);
            ss  += __shfl_xor(ss, 16);  ss  += __shfl_xor(ss, 32);
            const float mu  = sum * 0.015625f;
            const float var = ss * 0.015625f - mu * mu;
            const float inv = rsqrtf(var + 1e-5f);
            const float nmi = -mu * inv;

#pragma unroll
            for (int s = 0; s < 16; ++s) {
                float v = fmaf(fmaf(h[s], inv, nmi), gv[s], bbv[s]);
                h[s] = fmaxf(v, 0.f);
            }
            if (diag) {
                float bi[16];
                ld16f(bias, d0, d1, bi);
#pragma unroll
                for (int s = 0; s < 16; ++s) h[s] += bi[s];
            }

            // pack y fragments (B-operand: B[k=q*8+jj][n=ml] = y[j][d])
            const short8 a0 = pack8(h);
            const short8 a1 = pack8(h + 8);

            // MFMA -> swizzled LDS (conflict-free 2-way) -> 4x 1KB contiguous stores.
            // D^T: lane(q,ml) reg r = tile[j'=ml][o=ot*16+q*4+r].
#pragma unroll
            for (int ot = 0; ot < 4; ++ot) {
                f32x4 acc = b2q[ot];
                acc = __builtin_amdgcn_mfma_f32_16x16x32_bf16(bf[ot][0], a0, acc, 0, 0, 0);
                acc = __builtin_amdgcn_mfma_f32_16x16x32_bf16(bf[ot][1], a1, acc, 0, 0, 0);
                const int off = (ot * 16 + q * 4) ^ ((ml & 7) << 3);
                *(f32x4*)(ep + ml * 64 + off) = acc;
            }
            float* gb = out + (size_t)row * 8192 + jt * 1024;
#pragma unroll
            for (int c = 0; c < 4; ++c) {
                const int F  = c * 256 + lane * 4;     // linear float idx in 16x64 tile
                const int jl = F >> 6;
                const int o  = F & 63;
                f32x4 v = *(const f32x4*)(ep + jl * 64 + (o ^ ((jl & 7) << 3)));
                *(f32x4*)(gb + F) = v;
            }
        }
    }
}

extern "C" void kernel_launch(void* const* d_in, const int* in_sizes, int n_in,
                              void* d_out, int out_size, void* d_ws, size_t ws_size,
                              hipStream_t stream) {
    const float* x    = (const float*)d_in[0];
    const float* W1   = (const float*)d_in[1];
    const float* b1   = (const float*)d_in[2];
    const float* ln_g = (const float*)d_in[3];
    const float* ln_b = (const float*)d_in[4];
    const float* bias = (const float*)d_in[5];
    const float* W2   = (const float*)d_in[6];
    const float* b2   = (const float*)d_in[7];
    float* ws  = (float*)d_ws;
    float* out = (float*)d_out;

    hipLaunchKernelGGL(k_pre, dim3(544), dim3(192), 0, stream, x, W1, b1, ws);
    hipLaunchKernelGGL(k_main, dim3(1024), dim3(256), 0, stream,
                       ws, ln_g, ln_b, bias, W2, b2, out);
}